// Round 1
// baseline (89.214 us; speedup 1.0000x reference)
//
#include <hip/hip_runtime.h>
#include <math.h>

// Problem constants (from setup_inputs): B=16, F=4, K=16, Y=16, X=16, P=16, T=8
#define Bn 16
#define Fn 4
#define Kn 16
#define Yn 16
#define Xn 16
#define Pn 16
#define Tn 8

// One block per (b,f). 1024 threads: tid -> (yx = tid>>2, pq = tid&3).
// Each thread covers p in [4*pq, 4*pq+4), all t -> 32 contiguous floats of field.
__global__ __launch_bounds__(1024) void pkl_kernel(
    const float* __restrict__ field,   // (B,F,Y,X,P,T)
    const float* __restrict__ darea,   // (B,Y,X)
    const float* __restrict__ dlev,    // (B,P)
    const float* __restrict__ dtime,   // (B,T)
    const float* __restrict__ lat_mean, const float* __restrict__ lat_logstd,
    const float* __restrict__ lon_mean, const float* __restrict__ lon_logstd,
    const float* __restrict__ lev_mean, const float* __restrict__ lev_logstd,
    const float* __restrict__ time_logtau,
    float* __restrict__ out)           // (B, F*K)
{
    __shared__ float s_dareamean[Yn*Xn];
    __shared__ float s_klat[Kn*Yn], s_klon[Kn*Xn], s_klev[Kn*Pn], s_ktime[Kn*Tn];
    __shared__ float s_dlevmean[Pn], s_dtimemean[Tn];
    __shared__ float s_darea_b[Yn*Xn], s_dlev_b[Pn], s_dtime_b[Tn];
    __shared__ float s_part[Kn*Yn];
    __shared__ float s_inv[Kn];
    __shared__ float s_red[16][Kn];

    const int tid = threadIdx.x;
    const int bf  = blockIdx.x;      // b*Fn + f
    const int b   = bf >> 2;
    const int f   = bf & 3;

    // ---------------- setup phase (redundant per block; cheap) ----------------
    // batch-mean of darea + the three Gaussian 1D kernels
    if (tid < 256) {
        float s = 0.f;
        #pragma unroll
        for (int bb = 0; bb < Bn; ++bb) s += darea[bb*(Yn*Xn) + tid];
        s_dareamean[tid] = s * (1.f/16.f);
    } else if (tid < 512) {
        int i = tid - 256; int k = i >> 4; int y = i & 15;
        float m  = lat_mean[f*Kn + k];
        float sd = expf(lat_logstd[f*Kn + k]);
        float c  = -1.f + (float)y * (2.f/15.f);
        float z  = (c - m) / sd;
        s_klat[i] = expf(-0.5f * z * z);
    } else if (tid < 768) {
        int i = tid - 512; int k = i >> 4; int x = i & 15;
        float m  = lon_mean[f*Kn + k];
        float sd = expf(lon_logstd[f*Kn + k]);
        float c  = -1.f + (float)x * (2.f/15.f);
        float z  = (c - m) / sd;
        s_klon[i] = expf(-0.5f * z * z);
    } else {
        int i = tid - 768; int k = i >> 4; int p = i & 15;
        float m  = lev_mean[f*Kn + k];
        float sd = expf(lev_logstd[f*Kn + k]);
        float c  = -1.f + (float)p * (2.f/15.f);
        float z  = (c - m) / sd;
        s_klev[i] = expf(-0.5f * z * z);
    }
    // second batch of independent setup tasks (same phase, disjoint tid ranges)
    if (tid < 128) {
        int k = tid >> 3; int t = tid & 7;
        float tau = expf(time_logtau[f*Kn + k]) + 1e-4f;
        s_ktime[tid] = expf(-(float)t / tau);
    } else if (tid < 144) {
        int p = tid - 128;
        float s = 0.f;
        #pragma unroll
        for (int bb = 0; bb < Bn; ++bb) s += dlev[bb*Pn + p];
        s_dlevmean[p] = s * (1.f/16.f);
    } else if (tid < 152) {
        int t = tid - 144;
        float s = 0.f;
        #pragma unroll
        for (int bb = 0; bb < Bn; ++bb) s += dtime[bb*Tn + t];
        s_dtimemean[t] = s * (1.f/16.f);
    } else if (tid < 168) {
        int p = tid - 152;
        s_dlev_b[p] = dlev[b*Pn + p];
    } else if (tid < 176) {
        int t = tid - 168;
        s_dtime_b[t] = dtime[b*Tn + t];
    } else if (tid < 432) {
        int i = tid - 176;
        s_darea_b[i] = darea[b*(Yn*Xn) + i];
    }
    __syncthreads();

    // integral: S_area bilinear partials, one thread per (k,y)
    if (tid < 256) {
        int k = tid >> 4; int y = tid & 15;
        float s = 0.f;
        #pragma unroll
        for (int x = 0; x < Xn; ++x) s += s_klon[k*Xn + x] * s_dareamean[y*Xn + x];
        s_part[tid] = s_klat[k*Yn + y] * s;
    }
    __syncthreads();
    if (tid < Kn) {
        int k = tid;
        float sa = 0.f;
        #pragma unroll
        for (int y = 0; y < Yn; ++y) sa += s_part[k*Yn + y];
        float sl = 0.f;
        #pragma unroll
        for (int p = 0; p < Pn; ++p) sl += s_klev[k*Pn + p] * s_dlevmean[p];
        float st = 0.f;
        #pragma unroll
        for (int t = 0; t < Tn; ++t) st += s_ktime[k*Tn + t] * s_dtimemean[t];
        s_inv[k] = 1.f / (sa * sl * st + 1e-4f);
    }
    __syncthreads();

    // ---------------- main contraction ----------------
    const int yx = tid >> 2;     // 0..255
    const int pq = tid & 3;      // p-quad: p in [4*pq, 4*pq+4)
    const int y  = yx >> 4;
    const int x  = yx & 15;

    const float da = s_darea_b[yx];
    float dt[Tn];
    #pragma unroll
    for (int t = 0; t < Tn; ++t) dt[t] = s_dtime_b[t];

    // load 32 contiguous floats (lane-contiguous 128B stride), premultiply quad
    const float4* fptr = (const float4*)(field + (size_t)bf * (Yn*Xn*Pn*Tn) + (size_t)tid * 32);
    float w[4][Tn];
    #pragma unroll
    for (int pp = 0; pp < 4; ++pp) {
        float dl = s_dlev_b[pq*4 + pp] * da;
        float4 v0 = fptr[pp*2 + 0];
        float4 v1 = fptr[pp*2 + 1];
        w[pp][0] = v0.x * (dt[0] * dl);
        w[pp][1] = v0.y * (dt[1] * dl);
        w[pp][2] = v0.z * (dt[2] * dl);
        w[pp][3] = v0.w * (dt[3] * dl);
        w[pp][4] = v1.x * (dt[4] * dl);
        w[pp][5] = v1.y * (dt[5] * dl);
        w[pp][6] = v1.z * (dt[6] * dl);
        w[pp][7] = v1.w * (dt[7] * dl);
    }

    float acc[Kn];
    for (int k = 0; k < Kn; ++k) {
        float kt[Tn];
        #pragma unroll
        for (int t = 0; t < Tn; ++t) kt[t] = s_ktime[k*Tn + t];
        float s = 0.f;
        #pragma unroll
        for (int pp = 0; pp < 4; ++pp) {
            float tp = 0.f;
            #pragma unroll
            for (int t = 0; t < Tn; ++t) tp += w[pp][t] * kt[t];
            s += tp * s_klev[k*Pn + pq*4 + pp];
        }
        acc[k] = s * s_klat[k*Yn + y] * s_klon[k*Xn + x];
    }

    // ---------------- reduction: 16 values over 1024 threads ----------------
    #pragma unroll
    for (int k = 0; k < Kn; ++k) {
        float v = acc[k];
        #pragma unroll
        for (int off = 32; off > 0; off >>= 1) v += __shfl_xor(v, off, 64);
        acc[k] = v;
    }
    const int wave = tid >> 6;
    const int lane = tid & 63;
    if (lane == 0) {
        #pragma unroll
        for (int k = 0; k < Kn; ++k) s_red[wave][k] = acc[k];
    }
    __syncthreads();
    if (tid < Kn) {
        float s = 0.f;
        #pragma unroll
        for (int wv = 0; wv < 16; ++wv) s += s_red[wv][tid];
        out[b*(Fn*Kn) + f*Kn + tid] = s * s_inv[tid];
    }
}

extern "C" void kernel_launch(void* const* d_in, const int* in_sizes, int n_in,
                              void* d_out, int out_size, void* d_ws, size_t ws_size,
                              hipStream_t stream) {
    const float* field      = (const float*)d_in[0];
    const float* darea      = (const float*)d_in[1];
    const float* dlev       = (const float*)d_in[2];
    const float* dtime      = (const float*)d_in[3];
    const float* lat_mean   = (const float*)d_in[4];
    const float* lat_logstd = (const float*)d_in[5];
    const float* lon_mean   = (const float*)d_in[6];
    const float* lon_logstd = (const float*)d_in[7];
    const float* lev_mean   = (const float*)d_in[8];
    const float* lev_logstd = (const float*)d_in[9];
    const float* time_logtau= (const float*)d_in[10];
    float* out = (float*)d_out;

    pkl_kernel<<<Bn*Fn, 1024, 0, stream>>>(
        field, darea, dlev, dtime,
        lat_mean, lat_logstd, lon_mean, lon_logstd,
        lev_mean, lev_logstd, time_logtau, out);
}

// Round 2
// 84.636 us; speedup vs baseline: 1.0541x; 1.0541x over previous
//
#include <hip/hip_runtime.h>
#include <math.h>

// Problem constants: B=16, F=4, K=16, Y=16, X=16, P=16, T=8
#define Bn 16
#define Fn 4
#define Kn 16
#define Yn 16
#define Xn 16
#define Pn 16
#define Tn 8

// Grid = B*F*4 = 256 blocks (one per CU), 256 threads each.
// Block handles (b, f, yq): y rows [4*yq, 4*yq+4).
// tid -> (y_local = tid>>6, x = (tid>>2)&15, pq = tid&3); each thread owns
// 32 contiguous floats of field (p-quad x all t), so block reads a contiguous
// 32 KB slab with perfectly coalesced float4 loads.
__global__ __launch_bounds__(256) void pkl_kernel(
    const float* __restrict__ field,   // (B,F,Y,X,P,T)
    const float* __restrict__ darea,   // (B,Y,X)
    const float* __restrict__ dlev,    // (B,P)
    const float* __restrict__ dtime,   // (B,T)
    const float* __restrict__ lat_mean, const float* __restrict__ lat_logstd,
    const float* __restrict__ lon_mean, const float* __restrict__ lon_logstd,
    const float* __restrict__ lev_mean, const float* __restrict__ lev_logstd,
    const float* __restrict__ time_logtau,
    float* __restrict__ out)           // (B, F*K), pre-zeroed
{
    __shared__ float s_dareamean[Yn*Xn];
    __shared__ float s_klat[Kn*Yn], s_klon[Kn*Xn], s_klev[Kn*Pn], s_ktime[Kn*Tn];
    __shared__ float s_dlevmean[Pn], s_dtimemean[Tn];
    __shared__ float s_darea_b[4*Xn];          // only our 4 y-rows
    __shared__ float s_dlev_b[Pn], s_dtime_b[Tn];
    __shared__ float s_part[Kn*Yn];
    __shared__ float s_inv[Kn];
    __shared__ float s_red[4][Kn];

    const int tid = threadIdx.x;
    const int blk = blockIdx.x;
    const int bf  = blk >> 2;        // b*Fn + f
    const int yq  = blk & 3;         // y-quad
    const int b   = bf >> 2;
    const int f   = bf & 3;

    // ---------------- setup phase (one barrier phase, all tasks) ----------------
    {
        // batch-mean of darea: one (y,x) cell per thread
        float s = 0.f;
        #pragma unroll
        for (int bb = 0; bb < Bn; ++bb) s += darea[bb*(Yn*Xn) + tid];
        s_dareamean[tid] = s * (1.f/16.f);

        // the three Gaussian 1D kernels: one (k,i) entry of each per thread
        const int k = tid >> 4;
        const int i = tid & 15;
        const float c = -1.f + (float)i * (2.f/15.f);
        {
            float m  = lat_mean[f*Kn + k];
            float sd = expf(lat_logstd[f*Kn + k]);
            float z  = (c - m) / sd;
            s_klat[tid] = expf(-0.5f * z * z);
        }
        {
            float m  = lon_mean[f*Kn + k];
            float sd = expf(lon_logstd[f*Kn + k]);
            float z  = (c - m) / sd;
            s_klon[tid] = expf(-0.5f * z * z);
        }
        {
            float m  = lev_mean[f*Kn + k];
            float sd = expf(lev_logstd[f*Kn + k]);
            float z  = (c - m) / sd;
            s_klev[tid] = expf(-0.5f * z * z);
        }
    }
    if (tid < 128) {
        int k = tid >> 3; int t = tid & 7;
        float tau = expf(time_logtau[f*Kn + k]) + 1e-4f;
        s_ktime[tid] = expf(-(float)t / tau);
    } else if (tid < 144) {
        int p = tid - 128;
        float s = 0.f;
        #pragma unroll
        for (int bb = 0; bb < Bn; ++bb) s += dlev[bb*Pn + p];
        s_dlevmean[p] = s * (1.f/16.f);
    } else if (tid < 152) {
        int t = tid - 144;
        float s = 0.f;
        #pragma unroll
        for (int bb = 0; bb < Bn; ++bb) s += dtime[bb*Tn + t];
        s_dtimemean[t] = s * (1.f/16.f);
    } else if (tid < 168) {
        int p = tid - 152;
        s_dlev_b[p] = dlev[b*Pn + p];
    } else if (tid < 176) {
        int t = tid - 168;
        s_dtime_b[t] = dtime[b*Tn + t];
    } else if (tid < 240) {
        int i = tid - 176;   // 0..63 -> our 4 contiguous y-rows
        s_darea_b[i] = darea[b*(Yn*Xn) + yq*(4*Xn) + i];
    }
    __syncthreads();

    // integral: S_area bilinear partials, one thread per (k,y)
    {
        int k = tid >> 4; int y = tid & 15;
        float s = 0.f;
        #pragma unroll
        for (int x = 0; x < Xn; ++x) s += s_klon[k*Xn + x] * s_dareamean[y*Xn + x];
        s_part[tid] = s_klat[k*Yn + y] * s;
    }
    __syncthreads();
    if (tid < Kn) {
        int k = tid;
        float sa = 0.f;
        #pragma unroll
        for (int y = 0; y < Yn; ++y) sa += s_part[k*Yn + y];
        float sl = 0.f;
        #pragma unroll
        for (int p = 0; p < Pn; ++p) sl += s_klev[k*Pn + p] * s_dlevmean[p];
        float st = 0.f;
        #pragma unroll
        for (int t = 0; t < Tn; ++t) st += s_ktime[k*Tn + t] * s_dtimemean[t];
        s_inv[k] = 1.f / (sa * sl * st + 1e-4f);
    }
    __syncthreads();

    // ---------------- main contraction ----------------
    const int y_local = tid >> 6;          // 0..3
    const int x       = (tid >> 2) & 15;
    const int pq      = tid & 3;           // p in [4*pq, 4*pq+4)
    const int y       = yq*4 + y_local;

    const float da = s_darea_b[(y_local << 4) | x];
    float dt[Tn];
    #pragma unroll
    for (int t = 0; t < Tn; ++t) dt[t] = s_dtime_b[t];

    // 32 contiguous floats per thread; block slab is contiguous 32 KB
    const float4* fptr = (const float4*)(field + (size_t)bf * (Yn*Xn*Pn*Tn)
                                               + (size_t)yq * (4*Xn*Pn*Tn)
                                               + (size_t)tid * 32);
    float w[4][Tn];
    #pragma unroll
    for (int pp = 0; pp < 4; ++pp) {
        float dl = s_dlev_b[pq*4 + pp] * da;
        float4 v0 = fptr[pp*2 + 0];
        float4 v1 = fptr[pp*2 + 1];
        w[pp][0] = v0.x * (dt[0] * dl);
        w[pp][1] = v0.y * (dt[1] * dl);
        w[pp][2] = v0.z * (dt[2] * dl);
        w[pp][3] = v0.w * (dt[3] * dl);
        w[pp][4] = v1.x * (dt[4] * dl);
        w[pp][5] = v1.y * (dt[5] * dl);
        w[pp][6] = v1.z * (dt[6] * dl);
        w[pp][7] = v1.w * (dt[7] * dl);
    }

    float acc[Kn];
    for (int k = 0; k < Kn; ++k) {
        float kt[Tn];
        #pragma unroll
        for (int t = 0; t < Tn; ++t) kt[t] = s_ktime[k*Tn + t];
        float s = 0.f;
        #pragma unroll
        for (int pp = 0; pp < 4; ++pp) {
            float tp = 0.f;
            #pragma unroll
            for (int t = 0; t < Tn; ++t) tp += w[pp][t] * kt[t];
            s += tp * s_klev[k*Pn + pq*4 + pp];
        }
        acc[k] = s * s_klat[k*Yn + y] * s_klon[k*Xn + x];
    }

    // ---------------- reduction: 16 values over 4 waves ----------------
    #pragma unroll
    for (int k = 0; k < Kn; ++k) {
        float v = acc[k];
        #pragma unroll
        for (int off = 32; off > 0; off >>= 1) v += __shfl_xor(v, off, 64);
        acc[k] = v;
    }
    const int wave = tid >> 6;
    const int lane = tid & 63;
    if (lane == 0) {
        #pragma unroll
        for (int k = 0; k < Kn; ++k) s_red[wave][k] = acc[k];
    }
    __syncthreads();
    if (tid < Kn) {
        float s = s_red[0][tid] + s_red[1][tid] + s_red[2][tid] + s_red[3][tid];
        atomicAdd(&out[bf*Kn + tid], s * s_inv[tid]);
    }
}

extern "C" void kernel_launch(void* const* d_in, const int* in_sizes, int n_in,
                              void* d_out, int out_size, void* d_ws, size_t ws_size,
                              hipStream_t stream) {
    const float* field      = (const float*)d_in[0];
    const float* darea      = (const float*)d_in[1];
    const float* dlev       = (const float*)d_in[2];
    const float* dtime      = (const float*)d_in[3];
    const float* lat_mean   = (const float*)d_in[4];
    const float* lat_logstd = (const float*)d_in[5];
    const float* lon_mean   = (const float*)d_in[6];
    const float* lon_logstd = (const float*)d_in[7];
    const float* lev_mean   = (const float*)d_in[8];
    const float* lev_logstd = (const float*)d_in[9];
    const float* time_logtau= (const float*)d_in[10];
    float* out = (float*)d_out;

    // zero the accumulator output (harness poisons it with 0xAA)
    hipMemsetAsync(out, 0, (size_t)out_size * sizeof(float), stream);

    pkl_kernel<<<Bn*Fn*4, 256, 0, stream>>>(
        field, darea, dlev, dtime,
        lat_mean, lat_logstd, lon_mean, lon_logstd,
        lev_mean, lev_logstd, time_logtau, out);
}